// Round 6
// baseline (284.531 us; speedup 1.0000x reference)
//
#include <hip/hip_runtime.h>
#include <hip/hip_bf16.h>
#include <algorithm>
#include <vector>
#include <cmath>

#define HH 96
#define WW 96
#define CC 21
#define NN (HH*WW)          // 9216
#define NELEM (NN*CC)       // 193536
#define RS 20
#define NPAR (2*CC + CC*CC)
#define L2E 1.4426950408889634f
#define NSLOT 8
#define SROWS 12
#define NBLUR (CC*8)        // 168 blur items
#define TRUNC2 1225         // 35^2
#define BLURFLAG 0x40000000

typedef short bf16x8 __attribute__((ext_vector_type(8)));
typedef float f32x16 __attribute__((ext_vector_type(16)));

__device__ __forceinline__ float fexp2(float x) { return __builtin_amdgcn_exp2f(x); }
__device__ __forceinline__ float fexp(float x)  { return __builtin_amdgcn_exp2f(x * L2E); }

__device__ __forceinline__ short f2b(float f) {
    __hip_bfloat16 h = __float2bfloat16(f);
    short s; __builtin_memcpy(&s, &h, 2); return s;
}

// ---- dtype sniff: bf16 data never contains exp=0xFF bit patterns.
__global__ void k_sniff(const unsigned short* __restrict__ u16, int* __restrict__ flag32) {
    __shared__ int sfound;
    if (threadIdx.x == 0) sfound = 0;
    __syncthreads();
    const int base = blockIdx.x * (NELEM/32);
    int found = 0;
    for (int i = base + threadIdx.x; i < base + NELEM/32; i += 256) {
        unsigned v = u16[i];
        if ((v & 0x7F80u) == 0x7F80u) found = 1;
    }
    if (found) sfound = 1;
    __syncthreads();
    if (threadIdx.x == 0) flag32[blockIdx.x] = sfound;
}

__device__ __forceinline__ int rdflag(const int* __restrict__ flag32) {
    int f = 0;
    #pragma unroll
    for (int i = 0; i < 32; i++) f |= flag32[i];
    return f;
}

// Fused prep: featx, params, softmax(u)->pT, zero all bil slots.
__global__ __launch_bounds__(256) void k_prep(
    const void* __restrict__ u, const void* __restrict__ img,
    const void* __restrict__ wS, const void* __restrict__ wB,
    const void* __restrict__ compat, const int* __restrict__ flag32,
    float* __restrict__ uf, float* __restrict__ featx, float* __restrict__ par,
    float* __restrict__ bil8, __hip_bfloat16* __restrict__ pT)
{
    const int f = rdflag(flag32);
    const int tid = threadIdx.x;
    const int n = blockIdx.x * 256 + tid;

    if (blockIdx.x == 0) {
        for (int i = tid; i < NPAR; i += 256) {
            const void* src; int j;
            if (i < CC)        { src = wS;     j = i; }
            else if (i < 2*CC) { src = wB;     j = i - CC; }
            else               { src = compat; j = i - 2*CC; }
            par[i] = f ? ((const float*)src)[j]
                       : __bfloat162float(((const __hip_bfloat16*)src)[j]);
        }
    }
    {
        float c0, c1, c2;
        if (f) { const float* p = (const float*)img;
                 c0 = p[3*n]; c1 = p[3*n+1]; c2 = p[3*n+2]; }
        else   { const __hip_bfloat16* p = (const __hip_bfloat16*)img;
                 c0 = __bfloat162float(p[3*n]); c1 = __bfloat162float(p[3*n+1]);
                 c2 = __bfloat162float(p[3*n+2]); }
        float ym = (float)(n / WW), xm = (float)(n % WW);
        const float sc = 0.15014029f;   // sqrt(2*L2E/128)
        const float cf = 9.6089787f;    // sqrt(64*L2E)
        featx[8*n + 0] = -L2E * (fmaf(ym, ym, xm*xm) * 0.0078125f
                                 + 32.f * (c0*c0 + c1*c1 + c2*c2));
        featx[8*n + 1] = sc * ym;
        featx[8*n + 2] = sc * xm;
        featx[8*n + 3] = cf * c0;
        featx[8*n + 4] = cf * c1;
        featx[8*n + 5] = cf * c2;
        featx[8*n + 6] = 0.f;
        featx[8*n + 7] = 0.f;
    }

    float v[CC];
    float mx = -1e30f;
    #pragma unroll
    for (int c = 0; c < CC; c++) {
        float uv = f ? ((const float*)u)[n*CC + c]
                     : __bfloat162float(((const __hip_bfloat16*)u)[n*CC + c]);
        uf[n*CC + c] = uv;
        v[c] = uv;
        mx = fmaxf(mx, uv);
    }
    float s = 0.f;
    #pragma unroll
    for (int c = 0; c < CC; c++) { v[c] = fexp(v[c] - mx); s += v[c]; }
    float inv = 1.f / s;
    #pragma unroll
    for (int c = 0; c < CC; c++) {
        pT[(size_t)c*NN + n] = __float2bfloat16(v[c] * inv);
        #pragma unroll
        for (int sl = 0; sl < NSLOT; sl++)
            bil8[((size_t)sl*CC + c)*NN + n] = 0.f;
    }
}

// ---- blur body
__device__ __forceinline__ void blur_item(
    int b2, float* smem, const __hip_bfloat16* __restrict__ pT,
    float* __restrict__ s2T, int tid)
{
    float* A   = smem;           // up to 52 rows x 96
    float* B2  = smem + 4992;    // 12 x 96
    float* w_s = smem + 6144;    // 21 weights
    const int c = b2 % CC;
    const int strip = b2 / CC;
    const int y0 = strip * SROWS;
    const int ylo = (y0 - RS < 0) ? 0 : y0 - RS;
    const int yhi = (y0 + SROWS - 1 + RS > HH - 1) ? HH - 1 : y0 + SROWS - 1 + RS;
    const int nrows = yhi - ylo + 1;

    if (tid <= RS) w_s[tid] = fexp2(-(float)(tid*tid) * (L2E / 18.f));
    const __hip_bfloat16* src = pT + (size_t)c * NN + ylo * WW;
    for (int i = tid; i < nrows * WW; i += 256)
        A[i] = __bfloat162float(src[i]);
    __syncthreads();

    for (int i = tid; i < SROWS * WW; i += 256) {
        const int yo = y0 + i / WW;
        const int x  = i % WW;
        float acc = A[(yo - ylo) * WW + x];
        #pragma unroll
        for (int d = 1; d <= RS; d++) {
            float s = 0.f;
            if (yo - d >= 0)  s += A[(yo - d - ylo) * WW + x];
            if (yo + d < HH)  s += A[(yo + d - ylo) * WW + x];
            acc = fmaf(w_s[d], s, acc);
        }
        B2[i] = acc;
    }
    __syncthreads();

    for (int i = tid; i < SROWS * WW; i += 256) {
        const int r = i / WW, x = i % WW;
        float acc = B2[i];
        #pragma unroll
        for (int d = 1; d <= RS; d++) {
            float s = 0.f;
            if (x - d >= 0)  s += B2[r * WW + x - d];
            if (x + d < WW)  s += B2[r * WW + x + d];
            acc = fmaf(w_s[d], s, acc);
        }
        s2T[(size_t)c * NN + (y0 + r) * WW + x] = acc;
    }
}

// Merged work kernel: each bilateral block owns one n-tile PARTIAL (a list of
// m-chunks), accumulates in registers across chunks, and writes its private
// bil8 slot with plain coalesced stores. ZERO global atomics.
__global__ __launch_bounds__(256) void k_work(
    const __hip_bfloat16* __restrict__ pT, const float* __restrict__ featx,
    float* __restrict__ bil8, float* __restrict__ s2T,
    const int* __restrict__ hdr, const int* __restrict__ mcs)
{
    __shared__ float smem[6176];
    const int tid = threadIdx.x;
    const int item = hdr[blockIdx.x];

    if (!(item & BLURFLAG)) {
        const int nt   = item >> 18;
        const int slot = (item >> 15) & 7;
        const int off  = (item >> 5) & 1023;
        const int cnt  = item & 31;
        const int ny0 = (nt / 6) * 16, nx0 = (nt % 6) * 16;
        const int wv = tid >> 6, lane = tid & 63;
        const int quad = lane >> 5, lid = lane & 31;
        const int row = lid >> 4, col = lid & 15;
        const int by0 = ny0 + 4 * wv;
        const int n0 = (by0 + row) * WW + nx0 + col;
        const int n1 = n0 + 2 * WW;
        const float4 g0a = *(const float4*)(featx + (size_t)n0 * 8);
        const float4 g0b = *(const float4*)(featx + (size_t)n0 * 8 + 4);
        const float4 g1a = *(const float4*)(featx + (size_t)n1 * 8);
        const float4 g1b = *(const float4*)(featx + (size_t)n1 * 8 + 4);

        f32x16 acc0, acc1;
        #pragma unroll
        for (int r = 0; r < 16; r++) { acc0[r] = 0.f; acc1[r] = 0.f; }

        for (int ci = 0; ci < cnt; ci++) {
            const int mc = mcs[off + ci];
            const int my0 = (mc & 3) * 24, mx0 = (mc >> 2) * 16;
            const int dx = (mx0 > nx0 + 15) ? mx0 - (nx0 + 15)
                         : ((nx0 > mx0 + 15) ? nx0 - (mx0 + 15) : 0);
            const int lim = TRUNC2 - dx * dx;        // >= 0 (host-culled)
            int T = (int)sqrtf((float)lim);
            T -= (T * T > lim);
            T += ((T + 1) * (T + 1) <= lim);
            int blo = ny0 - T - my0;      blo = blo < 0 ? 0 : blo;
            int bhi = ny0 + 15 + T - my0; bhi = bhi > 23 ? 23 : bhi;

            __syncthreads();   // protect smem from previous chunk's readers
            {   // stage featx rows blo..bhi: [seg][16 px][8 floats]
                float4* dst = (float4*)smem;
                for (int i = blo * 32 + tid; i < (bhi + 1) * 32; i += 256) {
                    const int seg = i >> 5, o = i & 31;
                    dst[i] = ((const float4*)(featx +
                              (size_t)((my0 + seg) * WW + mx0) * 8))[o];
                }
            }
            __syncthreads();

            int lo = by0 - T - my0;     lo = lo < 0 ? 0 : lo;
            int hi = by0 + 3 + T - my0; hi = hi > 23 ? 23 : hi;
            if (lo <= hi) {                          // wave-uniform
                int mg = (my0 + lo) * WW + mx0 + quad * 8;
                #pragma unroll 1
                for (int step = lo; step <= hi; step++, mg += WW) {
                    bf16x8 afrag = *(const bf16x8*)(pT + (size_t)lid * NN + mg);
                    const float* h = smem + (step * 16 + quad * 8) * 8;
                    float kb0[8], kb1[8];
                    #pragma unroll
                    for (int j = 0; j < 8; j++) {
                        float4 ha = *(const float4*)(h + j * 8);
                        float4 hb = *(const float4*)(h + j * 8 + 4);
                        float s0 = g0a.x + ha.x;
                        s0 = fmaf(g0a.y, ha.y, s0); s0 = fmaf(g0a.z, ha.z, s0);
                        s0 = fmaf(g0a.w, ha.w, s0); s0 = fmaf(g0b.x, hb.x, s0);
                        s0 = fmaf(g0b.y, hb.y, s0);
                        kb0[j] = fexp2(s0);
                        float s1 = g1a.x + ha.x;
                        s1 = fmaf(g1a.y, ha.y, s1); s1 = fmaf(g1a.z, ha.z, s1);
                        s1 = fmaf(g1a.w, ha.w, s1); s1 = fmaf(g1b.x, hb.x, s1);
                        s1 = fmaf(g1b.y, hb.y, s1);
                        kb1[j] = fexp2(s1);
                    }
                    bf16x8 b0, b1;
                    #pragma unroll
                    for (int j = 0; j < 8; j++) { b0[j] = f2b(kb0[j]); b1[j] = f2b(kb1[j]); }
                    acc0 = __builtin_amdgcn_mfma_f32_32x32x16_bf16(afrag, b0, acc0, 0, 0, 0);
                    acc1 = __builtin_amdgcn_mfma_f32_32x32x16_bf16(afrag, b1, acc1, 0, 0, 0);
                }
            }
        }

        // D layout: col(n) = lid, row(c) = (r&3) + 8*(r>>2) + 4*quad
        #pragma unroll
        for (int r = 0; r < 16; r++) {
            int c = (r & 3) + 8 * (r >> 2) + 4 * quad;
            if (c < CC) {
                bil8[((size_t)slot*CC + c)*NN + n0] = acc0[r];   // plain stores
                bil8[((size_t)slot*CC + c)*NN + n1] = acc1[r];
            }
        }
    } else {
        blur_item(item & 0xFFFF, smem, pT, s2T, tid);
    }
}

// Combine 8 slots + spatial, compat, q-update, fused softmax -> pT.
__global__ __launch_bounds__(256) void k_update(
    float* __restrict__ bil8, const float* __restrict__ s2T,
    const float* __restrict__ uf, const float* __restrict__ par,
    const int* __restrict__ flag32,
    __hip_bfloat16* __restrict__ pT, void* __restrict__ out, int last)
{
    __shared__ float sc[CC*CC + 1];
    __shared__ float sws[CC], swb[CC];
    const int tid = threadIdx.x;
    for (int i = tid; i < CC*CC; i += 256) sc[i] = par[2*CC + i];
    if (tid == 0) sc[CC*CC] = 0.f;
    if (tid < CC) { sws[tid] = par[tid]; swb[tid] = par[CC + tid]; }
    __syncthreads();

    const int half = tid & 1;
    const int n = blockIdx.x * 128 + (tid >> 1);

    float msg[11];
    #pragma unroll
    for (int k = 0; k < 11; k++) {
        const int cp = 2*k + half;
        if (cp < CC) {
            float b = 0.f;
            #pragma unroll
            for (int sl = 0; sl < NSLOT; sl++)
                b += bil8[((size_t)sl*CC + cp)*NN + n];
            msg[k] = fmaf(s2T[(size_t)cp*NN + n], sws[cp], b * swb[cp]);
            #pragma unroll
            for (int sl = 0; sl < NSLOT; sl++)
                bil8[((size_t)sl*CC + cp)*NN + n] = 0.f;
        } else msg[k] = 0.f;
    }

    float pw[CC];
    #pragma unroll
    for (int c = 0; c < CC; c++) {
        float a = msg[0] * sc[c*CC + half];
        #pragma unroll
        for (int k = 1; k < 11; k++)
            a = fmaf(msg[k], sc[c*CC + 2*k + half], a);
        pw[c] = a;
    }
    #pragma unroll
    for (int c = 0; c < CC; c++)
        pw[c] += __shfl_xor(pw[c], 1, 64);

    float qv[CC];
    float mx = -1e30f;
    #pragma unroll
    for (int c = 0; c < CC; c++) {
        qv[c] = uf[(size_t)n*CC + c] - pw[c];
        mx = fmaxf(mx, qv[c]);
    }

    if (last) {
        const int is_f32 = rdflag(flag32);
        #pragma unroll
        for (int k = 0; k < 11; k++) {
            const int ce = 2*k, co = (k < 10) ? 2*k + 1 : 0;
            float v = half ? qv[co] : qv[ce];
            const int c = 2*k + half;
            if (c < CC) {
                if (is_f32) ((float*)out)[(size_t)n*CC + c] = v;
                else ((__hip_bfloat16*)out)[(size_t)n*CC + c] = __float2bfloat16(v);
            }
        }
    } else {
        float ex[11]; float ssum = 0.f;
        #pragma unroll
        for (int k = 0; k < 11; k++) {
            const int ce = 2*k, co = (k < 10) ? 2*k + 1 : 0;
            float v = half ? qv[co] : qv[ce];
            float e = fexp(v - mx);
            if (2*k + half < CC) ssum += e;
            ex[k] = e;
        }
        ssum += __shfl_xor(ssum, 1, 64);
        const float inv = 1.f / ssum;
        #pragma unroll
        for (int k = 0; k < 11; k++) {
            const int c = 2*k + half;
            if (c < CC) pT[(size_t)c*NN + n] = __float2bfloat16(ex[k] * inv);
        }
    }
}

extern "C" void kernel_launch(void* const* d_in, const int* in_sizes, int n_in,
                              void* d_out, int out_size, void* d_ws, size_t ws_size,
                              hipStream_t stream)
{
    // ---- static work table: per n-tile, bin-pack surviving m-chunks into
    // <=8 balanced blocks (register accumulation across chunks, private slot).
    static std::vector<int> h_buf;
    static int h_nb = 0;
    if (h_nb == 0) {
        struct Rec { int blur, b2, nt, slot; long load; std::vector<int> mc; };
        std::vector<Rec> recs;
        for (int nt = 0; nt < 36; nt++) {
            const int ny0 = (nt/6)*16, nx0 = (nt%6)*16;
            struct It { int mc; int cost; };
            std::vector<It> v; long tot = 0;
            for (int mc = 0; mc < 24; mc++) {
                const int my0 = (mc&3)*24, mx0 = (mc>>2)*16;
                const int dx = (mx0 > nx0+15) ? mx0-(nx0+15)
                             : ((nx0 > mx0+15) ? nx0-(mx0+15) : 0);
                const int lim = TRUNC2 - dx*dx;
                if (lim < 0) continue;
                int T = (int)std::sqrt((double)lim);
                while (T*T > lim) T--;
                while ((T+1)*(T+1) <= lim) T++;
                int cost = 0;
                for (int wv = 0; wv < 4; wv++) {
                    const int by0 = ny0 + 4*wv;
                    int lo = by0 - T - my0;     if (lo < 0)  lo = 0;
                    int hi = by0 + 3 + T - my0; if (hi > 23) hi = 23;
                    if (lo <= hi) cost += hi - lo + 1;
                }
                if (cost == 0) continue;
                v.push_back({mc, cost}); tot += cost;
            }
            if (v.empty()) continue;
            int nb = (int)std::min<long>(NSLOT, (tot + 159) / 160);
            if (nb > (int)v.size()) nb = (int)v.size();
            std::sort(v.begin(), v.end(),
                      [](const It& a, const It& b){ return a.cost > b.cost; });
            std::vector<Rec> bins(nb);
            for (int i = 0; i < nb; i++) { bins[i] = {0, 0, nt, i, 0, {}}; }
            for (auto& it : v) {
                int bmin = 0;
                for (int i = 1; i < nb; i++)
                    if (bins[i].load < bins[bmin].load) bmin = i;
                bins[bmin].load += it.cost;
                bins[bmin].mc.push_back(it.mc);
            }
            for (auto& b : bins) recs.push_back(std::move(b));
        }
        for (int b = 0; b < NBLUR; b++) recs.push_back({1, b, 0, 0, 20, {}});
        std::sort(recs.begin(), recs.end(),
                  [](const Rec& a, const Rec& b){ return a.load > b.load; });
        const int nb = (int)recs.size();
        h_buf.assign(nb, 0);
        int off = 0;
        for (int i = 0; i < nb; i++) {
            if (recs[i].blur) { h_buf[i] = BLURFLAG | recs[i].b2; continue; }
            const int cnt = (int)recs[i].mc.size();
            h_buf[i] = (recs[i].nt << 18) | (recs[i].slot << 15) | (off << 5) | cnt;
            for (int m : recs[i].mc) h_buf.push_back(m);
            off += cnt;
        }
        h_nb = nb;
    }

    float* ws = (float*)d_ws;
    int*   flag32 = (int*)ws;                    // [0..32)
    float* par    = ws + 32;                     // 483 used
    float* featx  = ws + 544;                    // NN*8 = 73728 floats
    __hip_bfloat16* pT = (__hip_bfloat16*)(ws + 74272);   // 32*NN bf16 = 147456 floats
    float* uf   = ws + 221728;                   // NELEM
    float* s2T  = uf + NELEM;                    // NELEM
    float* bil8 = s2T + NELEM;                   // NSLOT*NELEM = 1548288 (6.2 MB)
    int*   d_tab = (int*)(bil8 + (size_t)NSLOT*NELEM);

    hipMemcpyAsync(d_tab, h_buf.data(), h_buf.size() * sizeof(int),
                   hipMemcpyHostToDevice, stream);

    const int* d_hdr = d_tab;
    const int* d_mcs = d_tab + h_nb;

    k_sniff<<<32, 256, 0, stream>>>((const unsigned short*)d_in[0], flag32);
    k_prep<<<NN/256, 256, 0, stream>>>(d_in[0], d_in[1], d_in[2], d_in[3], d_in[4],
                                       flag32, uf, featx, par, bil8, pT);

    for (int it = 0; it < 5; it++) {
        k_work<<<h_nb, 256, 0, stream>>>(pT, featx, bil8, s2T, d_hdr, d_mcs);
        k_update<<<NN/128, 256, 0, stream>>>(bil8, s2T, uf, par, flag32,
                                             pT, d_out, (it == 4) ? 1 : 0);
    }
}